// Round 1
// baseline (350.099 us; speedup 1.0000x reference)
//
#include <hip/hip_runtime.h>
#include <hip/hip_bf16.h>
#include <hip/hip_fp8.h>
#include <cstdint>
#include <cstddef>

// Problem constants (x = (8192, 768) fp32)
#define GN 8192
#define GD 768           // elements per row; fp8 => 768 bytes per row
#define NB 64            // 128-row blocks
#define NTILE 2080       // NB*(NB+1)/2 triangular tiles
#define KI 12            // 768 / 64 : K-iterations, 64 bytes (one 32x32x64 MFMA) each

#define LOG2E 1.4426950408889634f
#define LN2 0.6931471805599453f

typedef __attribute__((ext_vector_type(4))) float f32x4;
typedef __attribute__((ext_vector_type(16))) float f32x16;
typedef __attribute__((ext_vector_type(8))) int i32x8;
typedef __attribute__((ext_vector_type(2))) long l64x2;  // one b128 = 16 fp8 bytes

typedef __attribute__((address_space(1))) const unsigned int gu32;
typedef __attribute__((address_space(3))) unsigned int lu32;

__device__ __forceinline__ void gl2lds16(const void* g, void* l) {
    // async global->LDS, 16B per lane; LDS dest is wave-uniform base + lane*16
    __builtin_amdgcn_global_load_lds((gu32*)g, (lu32*)l, 16, 0, 0);
}

// bare v_exp_f32 (exp2) -- the 1-inst hardware path
__device__ __forceinline__ float hexp2(float x) {
    return __builtin_amdgcn_exp2f(x);
}

// DPP rotate within each 16-lane row (VALU pipe, not DS): dpp_ctrl = 0x120|n.
template <int CTRL>
__device__ __forceinline__ float fdpp(float x) {
    return __int_as_float(__builtin_amdgcn_update_dpp(
        0, __float_as_int(x), CTRL, 0xF, 0xF, true));
}
__device__ __forceinline__ float qmax16(float v) {
    v = fmaxf(v, fdpp<0x128>(v));  // row_ror:8
    v = fmaxf(v, fdpp<0x124>(v));  // row_ror:4
    v = fmaxf(v, fdpp<0x122>(v));  // row_ror:2
    v = fmaxf(v, fdpp<0x121>(v));  // row_ror:1
    return v;
}
__device__ __forceinline__ float qsum16(float v) {
    v += fdpp<0x128>(v);
    v += fdpp<0x124>(v);
    v += fdpp<0x122>(v);
    v += fdpp<0x121>(v);
    return v;
}

// PROVEN swizzle (measured 1.9e5 conflicts), byte-identical to prior rounds:
// granule q (16B) of row r lands at ((r>>1)*128 + ((((r&1)<<2)|q)^((r>>1)&7))*16
__device__ __forceinline__ int swz(int r, int q) {
    return ((r >> 1) << 7) + (((((r & 1) << 2) | q) ^ ((r >> 1) & 7)) << 4);
}

// ---------------- Kernel 1: fp8 e4m3 quantize + row sum-of-squares of the
// DEQUANTIZED values (sim_ij = -||x^_i - x^_j||^2 - 100*diag exactly) -------
// HW conversion path: v_cvt_pk_fp8_f32 / v_cvt_f32_fp8 (guaranteed 1-inst,
// format-consistent with the f8f6f4 MFMA; RNE, no saturation for |x|<448).
__global__ __launch_bounds__(256) void prep_kernel(const float* __restrict__ x,
                                                   unsigned char* __restrict__ xq,
                                                   float* __restrict__ sq,
                                                   float* __restrict__ out) {
    if (blockIdx.x == 0 && threadIdx.x == 0) out[0] = 0.f;  // for combine's atomics
    const int w = threadIdx.x >> 6, lane = threadIdx.x & 63;
    const int row = blockIdx.x * 4 + w;
    const float4* xr = (const float4*)(x + (size_t)row * GD);
    unsigned int* xqr = (unsigned int*)(xq + (size_t)row * GD);
    float s = 0.f;
#pragma unroll
    for (int i = 0; i < 3; ++i) {
        float4 v = xr[lane + 64 * i];
        unsigned int pk = __builtin_amdgcn_cvt_pk_fp8_f32(v.x, v.y, 0, false);
        pk = __builtin_amdgcn_cvt_pk_fp8_f32(v.z, v.w, pk, true);
        float d0 = __builtin_amdgcn_cvt_f32_fp8(pk, 0);
        float d1 = __builtin_amdgcn_cvt_f32_fp8(pk, 1);
        float d2 = __builtin_amdgcn_cvt_f32_fp8(pk, 2);
        float d3 = __builtin_amdgcn_cvt_f32_fp8(pk, 3);
        s += d0 * d0 + d1 * d1 + d2 * d2 + d3 * d3;
        xqr[lane + 64 * i] = pk;
    }
#pragma unroll
    for (int off = 1; off < 64; off <<= 1) s += __shfl_xor(s, off);
    if (lane == 0) sq[row] = s;
}

// ------- Kernel 2: symmetric triangular tile GEMM (MX-fp8, scale=1.0) + entropy -------
// CHANGE vs prior round: 16x16x32_fp8 pairs -> mfma_scale_f32_32x32x64_f8f6f4
// with all E8M0 scales = 0x7f (1.0). Numerically identical inputs/products,
// 2x matrix-pipe rate, 8x fewer MFMA instructions. K-step stays 64 bytes, so
// staging / swizzle / LDS double-buffer are unchanged. 32x32 operand layout:
// A row = lane&31, k-half = lane>>5 -> read granules {2*hi, 2*hi+1} (bytes
// [32*hi, 32*hi+32) of the 64B chunk) == exact HW layout; A/B symmetric.
// C/D: col = lane&31, row = (reg&3) + 8*(reg>>2) + 4*(lane>>5)  (verified).
__global__ __launch_bounds__(256, 4) void sym_gemm_entropy(
    const unsigned char* __restrict__ xq, const float* __restrict__ sq,
    const float* __restrict__ taup, float* __restrict__ pm,
    float* __restrict__ ps, float* __restrict__ pt) {
    __shared__ __align__(16) char lds[32768];  // [A0 8K][B0 8K][A1 8K][B1 8K]
    float (*tmrg)[4][3] = (float (*)[4][3])lds;  // aliased; guarded by barrier

    const int tid = threadIdx.x;
    const int lane = tid & 63;
    const int w = tid >> 6;
    const int cl2 = lane & 31, hi = lane >> 5;

    const int b = blockIdx.x;
    int I = (int)((sqrtf(8.0f * (float)b + 1.0f) - 1.0f) * 0.5f);
    while ((I + 1) * (I + 2) / 2 <= b) ++I;
    while (I * (I + 1) / 2 > b) --I;
    const int J = b - I * (I + 1) / 2;
    const int row_base = I * 128;
    const int col_base = J * 128;
    const float taub = (*taup) * LOG2E;  // base-2 scale

    // staging decode (proven inverse-swizzle)
    const int bb = (tid & 7) ^ ((tid >> 3) & 7);
    const int sRow = ((tid >> 3) << 1) | (bb >> 2);  // 0..63
    const int sKb = (bb & 3) * 16;                   // byte offset in 64-B chunk
    const unsigned char* gA = xq + (size_t)(row_base + sRow) * GD + sKb;
    const unsigned char* gB = xq + (size_t)(col_base + sRow) * GD + sKb;

    // fragment LDS offsets: lane reads granules 2*hi, 2*hi+1 of its row
    int offA[2], offB[4][2];
#pragma unroll
    for (int g = 0; g < 2; ++g) offA[g] = swz(w * 32 + cl2, 2 * hi + g);
#pragma unroll
    for (int tj = 0; tj < 4; ++tj)
#pragma unroll
        for (int g = 0; g < 2; ++g) offB[tj][g] = swz(tj * 32 + cl2, 2 * hi + g);

    f32x16 acc[4];
#pragma unroll
    for (int j = 0; j < 4; ++j)
#pragma unroll
        for (int e = 0; e < 16; ++e) acc[j][e] = 0.f;

    // prologue: stage k=0 into buffer 0
    gl2lds16(gA, lds + tid * 16);
    gl2lds16(gA + (size_t)64 * GD, lds + 4096 + tid * 16);
    gl2lds16(gB, lds + 8192 + tid * 16);
    gl2lds16(gB + (size_t)64 * GD, lds + 12288 + tid * 16);

    union AB { l64x2 h[2]; i32x8 v; };

#pragma unroll 2
    for (int kk = 0; kk < KI; ++kk) {
        __syncthreads();  // buf[kk&1] staged; prior buf's ds_reads done

        // 1) read ALL fragments of this iter (10 x ds_read_b128)
        const char* Ab = lds + (kk & 1) * 16384;
        const char* Bb = Ab + 8192;
        AB aF;
        AB bF[4];
        aF.h[0] = *(const l64x2*)(Ab + offA[0]);
        aF.h[1] = *(const l64x2*)(Ab + offA[1]);
#pragma unroll
        for (int tj = 0; tj < 4; ++tj) {
            bF[tj].h[0] = *(const l64x2*)(Bb + offB[tj][0]);
            bF[tj].h[1] = *(const l64x2*)(Bb + offB[tj][1]);
        }

        // 2) stage k+1 into the other buffer; drains at the next barrier
        if (kk + 1 < KI) {
            char* An = lds + ((kk + 1) & 1) * 16384;
            const int ko = (kk + 1) * 64;  // bytes along K
            gl2lds16(gA + ko, An + tid * 16);
            gl2lds16(gA + (size_t)64 * GD + ko, An + 4096 + tid * 16);
            gl2lds16(gB + ko, An + 8192 + tid * 16);
            gl2lds16(gB + (size_t)64 * GD + ko, An + 12288 + tid * 16);
        }

        // 3) 4 MX MFMAs (K=64, fmt fp8/fp8, scales = 1.0 -> exact fp8 GEMM)
#pragma unroll
        for (int tj = 0; tj < 4; ++tj)
            acc[tj] = __builtin_amdgcn_mfma_scale_f32_32x32x64_f8f6f4(
                aF.v, bF[tj].v, acc[tj], 0, 0, 0, 0x7f7f7f7f, 0, 0x7f7f7f7f);
    }

    // ---------------- epilogue (base-2 state, base-cancelled deltas) ----------------
    const float t2 = 2.f * taub;
    const float pen = 100.f * taub;
    float ar[16];  // -taub * sq[row] for this lane's 16 rows
#pragma unroll
    for (int k = 0; k < 16; ++k) {
        int rl = (k & 3) + 8 * (k >> 2) + 4 * hi;  // row_local in [0,32)
        ar[k] = -taub * sq[row_base + w * 32 + rl];
    }
    float ac[4];  // -taub * sq[col] for this lane's 4 cols
#pragma unroll
    for (int tj = 0; tj < 4; ++tj) ac[tj] = -taub * sq[col_base + tj * 32 + cl2];

    float* pmJ = pm + (size_t)J * GN;
    float* psJ = ps + (size_t)J * GN;
    float* ptJ = pt + (size_t)J * GN;

    // ---- direct pass: reduce over cols (4 tj in-thread x 32 lanes); the row
    // term is uniform across the reduction -> cancels in d; added once to m ----
#pragma unroll
    for (int k = 0; k < 16; ++k) {
        const int rl = (k & 3) + 8 * (k >> 2) + 4 * hi;
        const int rg = row_base + w * 32 + rl;
        float uu[4];
        float mloc = -1e30f;
        if (I == J) {  // block-uniform: only diagonal tiles carry the penalty
#pragma unroll
            for (int tj = 0; tj < 4; ++tj) {
                float u = fmaf(t2, acc[tj][k], ac[tj]);
                if (rg == col_base + tj * 32 + cl2) u -= pen;
                uu[tj] = u;
                mloc = fmaxf(mloc, u);
            }
        } else {
#pragma unroll
            for (int tj = 0; tj < 4; ++tj) {
                float u = fmaf(t2, acc[tj][k], ac[tj]);
                uu[tj] = u;
                mloc = fmaxf(mloc, u);
            }
        }
        mloc = fmaxf(mloc, __shfl_xor(mloc, 16));  // 32-wide max: xor16 + 16-lane DPP tree
        mloc = qmax16(mloc);
        float s = 0.f, t = 0.f;
#pragma unroll
        for (int tj = 0; tj < 4; ++tj) {
            float d = uu[tj] - mloc;  // row term cancelled
            float e = hexp2(d);       // bare v_exp_f32
            s += e;
            t += e * d;
        }
        s += __shfl_xor(s, 16);
        t += __shfl_xor(t, 16);
        s = qsum16(s);
        t = qsum16(t);
        if (cl2 == 0) {  // lanes 0 and 32 write disjoint rows
            pmJ[rg] = mloc + ar[k];  // base restored once
            psJ[rg] = s;
            ptJ[rg] = t;
        }
    }

    // ---- transposed pass: reduce over rows (16 in-thread x 2 hi-halves); col
    // term uniform across the reduction -> cancels in d; added once to m ----
    if (I != J) {  // block-uniform branch
        __syncthreads();  // all K-loop LDS reads done before tmrg aliases the buffer
#pragma unroll
        for (int tj = 0; tj < 4; ++tj) {
            float uu[16];
            float mloc = -1e30f;
#pragma unroll
            for (int k = 0; k < 16; ++k) {
                float u = fmaf(t2, acc[tj][k], ar[k]);
                uu[k] = u;
                mloc = fmaxf(mloc, u);
            }
            mloc = fmaxf(mloc, __shfl_xor(mloc, 32));  // combine hi-halves
            float s = 0.f, t = 0.f;
#pragma unroll
            for (int k = 0; k < 16; ++k) {
                float d = uu[k] - mloc;
                float e = hexp2(d);
                s += e;
                t += e * d;
            }
            s += __shfl_xor(s, 32);
            t += __shfl_xor(t, 32);
            if (hi == 0) {
                int c = tj * 32 + cl2;
                tmrg[c][w][0] = mloc + ac[tj];  // col term restored once
                tmrg[c][w][1] = s;
                tmrg[c][w][2] = t;
            }
        }
        __syncthreads();
        if (tid < 128) {
            float m = tmrg[tid][0][0], S = tmrg[tid][0][1], T = tmrg[tid][0][2];
#pragma unroll
            for (int ww = 1; ww < 4; ++ww) {
                float mc = tmrg[tid][ww][0], Sc = tmrg[tid][ww][1], Tc = tmrg[tid][ww][2];
                float mn = fmaxf(m, mc);
                float ea = hexp2(m - mn), eb = hexp2(mc - mn);
                T = (T + (m - mn) * S) * ea + (Tc + (mc - mn) * Sc) * eb;
                S = S * ea + Sc * eb;
                m = mn;
            }
            int c = col_base + tid;
            pm[(size_t)I * GN + c] = m;
            ps[(size_t)I * GN + c] = S;
            pt[(size_t)I * GN + c] = T;
        }
    }
}

// ------- Kernel 3: combine (base-2), coalesced + parallel -------
// entropy = ln2 * (log2(S) - T2/S); ln2 folded into the final atomic constant.
__global__ __launch_bounds__(256) void combine(const float* __restrict__ pm,
                                               const float* __restrict__ ps,
                                               const float* __restrict__ pt,
                                               const float* __restrict__ coefp,
                                               float* __restrict__ out) {
    const int t = threadIdx.x;
    const int r = t & 63;
    const int chunk = t >> 6;
    const int row = blockIdx.x * 64 + r;
    float m = -1e30f, S = 0.f, T = 0.f;
#pragma unroll
    for (int i = 0; i < 16; ++i) {
        const int c = chunk * 16 + i;
        float mc = pm[(size_t)c * GN + row];
        float Sc = ps[(size_t)c * GN + row];
        float Tc = pt[(size_t)c * GN + row];
        float mn = fmaxf(m, mc);
        float ea = __builtin_amdgcn_exp2f(m - mn), eb = __builtin_amdgcn_exp2f(mc - mn);
        T = (T + (m - mn) * S) * ea + (Tc + (mc - mn) * Sc) * eb;
        S = S * ea + Sc * eb;
        m = mn;
    }
    __shared__ float lm[4][64], lS[4][64], lT[4][64];
    lm[chunk][r] = m;
    lS[chunk][r] = S;
    lT[chunk][r] = T;
    __syncthreads();
    if (t < 64) {
        float M = lm[0][r], Sa = lS[0][r], Ta = lT[0][r];
#pragma unroll
        for (int cc = 1; cc < 4; ++cc) {
            float mc = lm[cc][r], Sc = lS[cc][r], Tc = lT[cc][r];
            float mn = fmaxf(M, mc);
            float ea = __builtin_amdgcn_exp2f(M - mn), eb = __builtin_amdgcn_exp2f(mc - mn);
            Ta = (Ta + (M - mn) * Sa) * ea + (Tc + (mc - mn) * Sc) * eb;
            Sa = Sa * ea + Sc * eb;
            M = mn;
        }
        float ent2 = __log2f(Sa) - Ta / Sa;  // base-2 row entropy (v_log_f32)
#pragma unroll
        for (int off = 1; off < 64; off <<= 1) ent2 += __shfl_xor(ent2, off);
        if (t == 0) atomicAdd(out, ent2 * coefp[0] * (LN2 / (float)GN));
    }
}

extern "C" void kernel_launch(void* const* d_in, const int* in_sizes, int n_in,
                              void* d_out, int out_size, void* d_ws, size_t ws_size,
                              hipStream_t stream) {
    const float* x = (const float*)d_in[0];      // 8192*768 fp32
    const float* coefp = (const float*)d_in[1];  // scalar
    const float* taup = (const float*)d_in[2];   // scalar
    float* out = (float*)d_out;

    char* ws = (char*)d_ws;
    unsigned char* xq = (unsigned char*)ws;              // 6,291,456 B (fp8)
    float* sq = (float*)(ws + 6291456);                  // 32,768 B
    float* pm = (float*)(ws + 6324224);                  // 2,097,152 B
    float* ps = (float*)(ws + 6324224 + 2097152);        // 2,097,152 B
    float* pt = (float*)(ws + 6324224 + 2 * 2097152);    // 2,097,152 B

    prep_kernel<<<GN / 4, 256, 0, stream>>>(x, xq, sq, out);
    sym_gemm_entropy<<<NTILE, 256, 0, stream>>>(xq, sq, taup, pm, ps, pt);
    combine<<<GN / 64, 256, 0, stream>>>(pm, ps, pt, coefp, out);
}

// Round 2
// 347.976 us; speedup vs baseline: 1.0061x; 1.0061x over previous
//
#include <hip/hip_runtime.h>
#include <hip/hip_bf16.h>
#include <hip/hip_fp8.h>
#include <cstdint>
#include <cstddef>

// Problem constants (x = (8192, 768) fp32)
#define GN 8192
#define GD 768           // elements per row; fp8 => 768 bytes per row
#define NB 64            // 128-row blocks
#define NTILE 2080       // NB*(NB+1)/2 triangular tiles
#define KI 12            // 768 / 64 : K-iterations, 64 bytes (one 32x32x64 MFMA) each

#define LOG2E 1.4426950408889634f
#define LN2 0.6931471805599453f

typedef __attribute__((ext_vector_type(4))) float f32x4;
typedef __attribute__((ext_vector_type(16))) float f32x16;
typedef __attribute__((ext_vector_type(4))) int i32x4;
typedef __attribute__((ext_vector_type(8))) int i32x8;

typedef __attribute__((address_space(1))) const unsigned int gu32;
typedef __attribute__((address_space(3))) unsigned int lu32;

__device__ __forceinline__ void gl2lds16(const void* g, void* l) {
    // async global->LDS, 16B per lane; LDS dest is wave-uniform base + lane*16
    __builtin_amdgcn_global_load_lds((gu32*)g, (lu32*)l, 16, 0, 0);
}

// bare v_exp_f32 (exp2) -- the 1-inst hardware path
__device__ __forceinline__ float hexp2(float x) {
    return __builtin_amdgcn_exp2f(x);
}

// DPP rotate within each 16-lane row (VALU pipe, not DS): dpp_ctrl = 0x120|n.
template <int CTRL>
__device__ __forceinline__ float fdpp(float x) {
    return __int_as_float(__builtin_amdgcn_update_dpp(
        0, __float_as_int(x), CTRL, 0xF, 0xF, true));
}
__device__ __forceinline__ float qmax16(float v) {
    v = fmaxf(v, fdpp<0x128>(v));  // row_ror:8
    v = fmaxf(v, fdpp<0x124>(v));  // row_ror:4
    v = fmaxf(v, fdpp<0x122>(v));  // row_ror:2
    v = fmaxf(v, fdpp<0x121>(v));  // row_ror:1
    return v;
}
__device__ __forceinline__ float qsum16(float v) {
    v += fdpp<0x128>(v);
    v += fdpp<0x124>(v);
    v += fdpp<0x122>(v);
    v += fdpp<0x121>(v);
    return v;
}

// PROVEN swizzle (measured 1.9e5 conflicts), byte-identical to prior rounds:
// granule q (16B) of row r lands at ((r>>1)*128 + ((((r&1)<<2)|q)^((r>>1)&7))*16
__device__ __forceinline__ int swz(int r, int q) {
    return ((r >> 1) << 7) + (((((r & 1) << 2) | q) ^ ((r >> 1) & 7)) << 4);
}

// ---------------- Kernel 1: fp8 e4m3 quantize + row sum-of-squares of the
// DEQUANTIZED values (sim_ij = -||x^_i - x^_j||^2 - 100*diag exactly) -------
__global__ __launch_bounds__(256) void prep_kernel(const float* __restrict__ x,
                                                   unsigned char* __restrict__ xq,
                                                   float* __restrict__ sq,
                                                   float* __restrict__ out) {
    if (blockIdx.x == 0 && threadIdx.x == 0) out[0] = 0.f;  // for combine's atomics
    const int w = threadIdx.x >> 6, lane = threadIdx.x & 63;
    const int row = blockIdx.x * 4 + w;
    const float4* xr = (const float4*)(x + (size_t)row * GD);
    unsigned int* xqr = (unsigned int*)(xq + (size_t)row * GD);
    float s = 0.f;
#pragma unroll
    for (int i = 0; i < 3; ++i) {
        float4 v = xr[lane + 64 * i];
        unsigned int pk = __builtin_amdgcn_cvt_pk_fp8_f32(v.x, v.y, 0, false);
        pk = __builtin_amdgcn_cvt_pk_fp8_f32(v.z, v.w, pk, true);
        float d0 = __builtin_amdgcn_cvt_f32_fp8(pk, 0);
        float d1 = __builtin_amdgcn_cvt_f32_fp8(pk, 1);
        float d2 = __builtin_amdgcn_cvt_f32_fp8(pk, 2);
        float d3 = __builtin_amdgcn_cvt_f32_fp8(pk, 3);
        s += d0 * d0 + d1 * d1 + d2 * d2 + d3 * d3;
        xqr[lane + 64 * i] = pk;
    }
#pragma unroll
    for (int off = 1; off < 64; off <<= 1) s += __shfl_xor(s, off);
    if (lane == 0) sq[row] = s;
}

// ------- Kernel 2: symmetric triangular tile GEMM (MX-fp8, scale=1.0) + entropy -------
// Round-1 post-mortem: the union-based operand assembly forced an alloca ->
// scratch spills (WRITE_SIZE 710 MB). Same MX math, but operands are now built
// with __builtin_shufflevector from two i32x4 LDS loads -- pure register
// concatenation, no in-memory aggregate anywhere.
// 32x32x64 operand layout: row = lane&31, k-half = lane>>5 -> granules
// {2*hi, 2*hi+1}. C/D: col = lane&31, row = (reg&3)+8*(reg>>2)+4*(lane>>5).
__global__ __launch_bounds__(256, 4) void sym_gemm_entropy(
    const unsigned char* __restrict__ xq, const float* __restrict__ sq,
    const float* __restrict__ taup, float* __restrict__ pm,
    float* __restrict__ ps, float* __restrict__ pt) {
    __shared__ __align__(16) char lds[32768];  // [A0 8K][B0 8K][A1 8K][B1 8K]
    float (*tmrg)[4][3] = (float (*)[4][3])lds;  // aliased; guarded by barrier

    const int tid = threadIdx.x;
    const int lane = tid & 63;
    const int w = tid >> 6;
    const int cl2 = lane & 31, hi = lane >> 5;

    const int b = blockIdx.x;
    int I = (int)((sqrtf(8.0f * (float)b + 1.0f) - 1.0f) * 0.5f);
    while ((I + 1) * (I + 2) / 2 <= b) ++I;
    while (I * (I + 1) / 2 > b) --I;
    const int J = b - I * (I + 1) / 2;
    const int row_base = I * 128;
    const int col_base = J * 128;
    const float taub = (*taup) * LOG2E;  // base-2 scale

    // staging decode (proven inverse-swizzle)
    const int bb = (tid & 7) ^ ((tid >> 3) & 7);
    const int sRow = ((tid >> 3) << 1) | (bb >> 2);  // 0..63
    const int sKb = (bb & 3) * 16;                   // byte offset in 64-B chunk
    const unsigned char* gA = xq + (size_t)(row_base + sRow) * GD + sKb;
    const unsigned char* gB = xq + (size_t)(col_base + sRow) * GD + sKb;

    // fragment LDS offsets: lane reads granules 2*hi, 2*hi+1 of its row
    int offA[2], offB[4][2];
#pragma unroll
    for (int g = 0; g < 2; ++g) offA[g] = swz(w * 32 + cl2, 2 * hi + g);
#pragma unroll
    for (int tj = 0; tj < 4; ++tj)
#pragma unroll
        for (int g = 0; g < 2; ++g) offB[tj][g] = swz(tj * 32 + cl2, 2 * hi + g);

    f32x16 acc[4];
#pragma unroll
    for (int j = 0; j < 4; ++j)
#pragma unroll
        for (int e = 0; e < 16; ++e) acc[j][e] = 0.f;

    // prologue: stage k=0 into buffer 0
    gl2lds16(gA, lds + tid * 16);
    gl2lds16(gA + (size_t)64 * GD, lds + 4096 + tid * 16);
    gl2lds16(gB, lds + 8192 + tid * 16);
    gl2lds16(gB + (size_t)64 * GD, lds + 12288 + tid * 16);

#pragma unroll 2
    for (int kk = 0; kk < KI; ++kk) {
        __syncthreads();  // buf[kk&1] staged; prior buf's ds_reads done

        // 1) read ALL fragments of this iter (10 x ds_read_b128); assemble
        //    i32x8 operands via shufflevector (registers only, no alloca)
        const char* Ab = lds + (kk & 1) * 16384;
        const char* Bb = Ab + 8192;
        i32x4 aL = *(const i32x4*)(Ab + offA[0]);
        i32x4 aH = *(const i32x4*)(Ab + offA[1]);
        i32x8 av = __builtin_shufflevector(aL, aH, 0, 1, 2, 3, 4, 5, 6, 7);
        i32x8 bv[4];
#pragma unroll
        for (int tj = 0; tj < 4; ++tj) {
            i32x4 bL = *(const i32x4*)(Bb + offB[tj][0]);
            i32x4 bH = *(const i32x4*)(Bb + offB[tj][1]);
            bv[tj] = __builtin_shufflevector(bL, bH, 0, 1, 2, 3, 4, 5, 6, 7);
        }

        // 2) stage k+1 into the other buffer; drains at the next barrier
        if (kk + 1 < KI) {
            char* An = lds + ((kk + 1) & 1) * 16384;
            const int ko = (kk + 1) * 64;  // bytes along K
            gl2lds16(gA + ko, An + tid * 16);
            gl2lds16(gA + (size_t)64 * GD + ko, An + 4096 + tid * 16);
            gl2lds16(gB + ko, An + 8192 + tid * 16);
            gl2lds16(gB + (size_t)64 * GD + ko, An + 12288 + tid * 16);
        }

        // 3) 4 MX MFMAs (K=64, fmt fp8/fp8, scales = 1.0 -> exact fp8 GEMM)
#pragma unroll
        for (int tj = 0; tj < 4; ++tj)
            acc[tj] = __builtin_amdgcn_mfma_scale_f32_32x32x64_f8f6f4(
                av, bv[tj], acc[tj], 0, 0, 0, 0x7f7f7f7f, 0, 0x7f7f7f7f);
    }

    // ---------------- epilogue (base-2 state, base-cancelled deltas) ----------------
    const float t2 = 2.f * taub;
    const float pen = 100.f * taub;
    float ar[16];  // -taub * sq[row] for this lane's 16 rows
#pragma unroll
    for (int k = 0; k < 16; ++k) {
        int rl = (k & 3) + 8 * (k >> 2) + 4 * hi;  // row_local in [0,32)
        ar[k] = -taub * sq[row_base + w * 32 + rl];
    }
    float ac[4];  // -taub * sq[col] for this lane's 4 cols
#pragma unroll
    for (int tj = 0; tj < 4; ++tj) ac[tj] = -taub * sq[col_base + tj * 32 + cl2];

    float* pmJ = pm + (size_t)J * GN;
    float* psJ = ps + (size_t)J * GN;
    float* ptJ = pt + (size_t)J * GN;

    // ---- direct pass: reduce over cols (4 tj in-thread x 32 lanes); the row
    // term is uniform across the reduction -> cancels in d; added once to m ----
#pragma unroll
    for (int k = 0; k < 16; ++k) {
        const int rl = (k & 3) + 8 * (k >> 2) + 4 * hi;
        const int rg = row_base + w * 32 + rl;
        float uu[4];
        float mloc = -1e30f;
        if (I == J) {  // block-uniform: only diagonal tiles carry the penalty
#pragma unroll
            for (int tj = 0; tj < 4; ++tj) {
                float u = fmaf(t2, acc[tj][k], ac[tj]);
                if (rg == col_base + tj * 32 + cl2) u -= pen;
                uu[tj] = u;
                mloc = fmaxf(mloc, u);
            }
        } else {
#pragma unroll
            for (int tj = 0; tj < 4; ++tj) {
                float u = fmaf(t2, acc[tj][k], ac[tj]);
                uu[tj] = u;
                mloc = fmaxf(mloc, u);
            }
        }
        mloc = fmaxf(mloc, __shfl_xor(mloc, 16));  // 32-wide max: xor16 + DPP tree
        mloc = qmax16(mloc);
        float s = 0.f, t = 0.f;
#pragma unroll
        for (int tj = 0; tj < 4; ++tj) {
            float d = uu[tj] - mloc;  // row term cancelled
            float e = hexp2(d);       // bare v_exp_f32
            s += e;
            t += e * d;
        }
        s += __shfl_xor(s, 16);
        t += __shfl_xor(t, 16);
        s = qsum16(s);
        t = qsum16(t);
        if (cl2 == 0) {  // lanes 0 and 32 write disjoint rows
            pmJ[rg] = mloc + ar[k];  // base restored once
            psJ[rg] = s;
            ptJ[rg] = t;
        }
    }

    // ---- transposed pass: reduce over rows (16 in-thread x 2 hi-halves); col
    // term uniform across the reduction -> cancels in d; added once to m ----
    if (I != J) {  // block-uniform branch
        __syncthreads();  // all K-loop LDS reads done before tmrg aliases the buffer
#pragma unroll
        for (int tj = 0; tj < 4; ++tj) {
            float uu[16];
            float mloc = -1e30f;
#pragma unroll
            for (int k = 0; k < 16; ++k) {
                float u = fmaf(t2, acc[tj][k], ar[k]);
                uu[k] = u;
                mloc = fmaxf(mloc, u);
            }
            mloc = fmaxf(mloc, __shfl_xor(mloc, 32));  // combine hi-halves
            float s = 0.f, t = 0.f;
#pragma unroll
            for (int k = 0; k < 16; ++k) {
                float d = uu[k] - mloc;
                float e = hexp2(d);
                s += e;
                t += e * d;
            }
            s += __shfl_xor(s, 32);
            t += __shfl_xor(t, 32);
            if (hi == 0) {
                int c = tj * 32 + cl2;
                tmrg[c][w][0] = mloc + ac[tj];  // col term restored once
                tmrg[c][w][1] = s;
                tmrg[c][w][2] = t;
            }
        }
        __syncthreads();
        if (tid < 128) {
            float m = tmrg[tid][0][0], S = tmrg[tid][0][1], T = tmrg[tid][0][2];
#pragma unroll
            for (int ww = 1; ww < 4; ++ww) {
                float mc = tmrg[tid][ww][0], Sc = tmrg[tid][ww][1], Tc = tmrg[tid][ww][2];
                float mn = fmaxf(m, mc);
                float ea = hexp2(m - mn), eb = hexp2(mc - mn);
                T = (T + (m - mn) * S) * ea + (Tc + (mc - mn) * Sc) * eb;
                S = S * ea + Sc * eb;
                m = mn;
            }
            int c = col_base + tid;
            pm[(size_t)I * GN + c] = m;
            ps[(size_t)I * GN + c] = S;
            pt[(size_t)I * GN + c] = T;
        }
    }
}

// ------- Kernel 3: combine (base-2), coalesced + parallel -------
__global__ __launch_bounds__(256) void combine(const float* __restrict__ pm,
                                               const float* __restrict__ ps,
                                               const float* __restrict__ pt,
                                               const float* __restrict__ coefp,
                                               float* __restrict__ out) {
    const int t = threadIdx.x;
    const int r = t & 63;
    const int chunk = t >> 6;
    const int row = blockIdx.x * 64 + r;
    float m = -1e30f, S = 0.f, T = 0.f;
#pragma unroll
    for (int i = 0; i < 16; ++i) {
        const int c = chunk * 16 + i;
        float mc = pm[(size_t)c * GN + row];
        float Sc = ps[(size_t)c * GN + row];
        float Tc = pt[(size_t)c * GN + row];
        float mn = fmaxf(m, mc);
        float ea = __builtin_amdgcn_exp2f(m - mn), eb = __builtin_amdgcn_exp2f(mc - mn);
        T = (T + (m - mn) * S) * ea + (Tc + (mc - mn) * Sc) * eb;
        S = S * ea + Sc * eb;
        m = mn;
    }
    __shared__ float lm[4][64], lS[4][64], lT[4][64];
    lm[chunk][r] = m;
    lS[chunk][r] = S;
    lT[chunk][r] = T;
    __syncthreads();
    if (t < 64) {
        float M = lm[0][r], Sa = lS[0][r], Ta = lT[0][r];
#pragma unroll
        for (int cc = 1; cc < 4; ++cc) {
            float mc = lm[cc][r], Sc = lS[cc][r], Tc = lT[cc][r];
            float mn = fmaxf(M, mc);
            float ea = __builtin_amdgcn_exp2f(M - mn), eb = __builtin_amdgcn_exp2f(mc - mn);
            Ta = (Ta + (M - mn) * Sa) * ea + (Tc + (mc - mn) * Sc) * eb;
            Sa = Sa * ea + Sc * eb;
            M = mn;
        }
        float ent2 = __log2f(Sa) - Ta / Sa;  // base-2 row entropy (v_log_f32)
#pragma unroll
        for (int off = 1; off < 64; off <<= 1) ent2 += __shfl_xor(ent2, off);
        if (t == 0) atomicAdd(out, ent2 * coefp[0] * (LN2 / (float)GN));
    }
}

extern "C" void kernel_launch(void* const* d_in, const int* in_sizes, int n_in,
                              void* d_out, int out_size, void* d_ws, size_t ws_size,
                              hipStream_t stream) {
    const float* x = (const float*)d_in[0];      // 8192*768 fp32
    const float* coefp = (const float*)d_in[1];  // scalar
    const float* taup = (const float*)d_in[2];   // scalar
    float* out = (float*)d_out;

    char* ws = (char*)d_ws;
    unsigned char* xq = (unsigned char*)ws;              // 6,291,456 B (fp8)
    float* sq = (float*)(ws + 6291456);                  // 32,768 B
    float* pm = (float*)(ws + 6324224);                  // 2,097,152 B
    float* ps = (float*)(ws + 6324224 + 2097152);        // 2,097,152 B
    float* pt = (float*)(ws + 6324224 + 2 * 2097152);    // 2,097,152 B

    prep_kernel<<<GN / 4, 256, 0, stream>>>(x, xq, sq, out);
    sym_gemm_entropy<<<NTILE, 256, 0, stream>>>(xq, sq, taup, pm, ps, pt);
    combine<<<GN / 64, 256, 0, stream>>>(pm, ps, pt, coefp, out);
}

// Round 3
// 132.495 us; speedup vs baseline: 2.6424x; 2.6263x over previous
//
#include <hip/hip_runtime.h>
#include <hip/hip_bf16.h>
#include <hip/hip_fp8.h>
#include <cstdint>
#include <cstddef>

// Problem constants (x = (8192, 768) fp32)
#define GN 8192
#define GD 768           // elements per row; fp8 => 768 bytes per row
#define NB 64            // 128-row blocks
#define NTILE 2080       // NB*(NB+1)/2 triangular tiles
#define KI 12            // 768 / 64 : K-iterations, 64 bytes (one 32x32x64 MFMA) each

#define LOG2E 1.4426950408889634f
#define LN2 0.6931471805599453f

typedef __attribute__((ext_vector_type(4))) float f32x4;
typedef __attribute__((ext_vector_type(16))) float f32x16;
typedef __attribute__((ext_vector_type(4))) int i32x4;
typedef __attribute__((ext_vector_type(8))) int i32x8;

typedef __attribute__((address_space(1))) const unsigned int gu32;
typedef __attribute__((address_space(3))) unsigned int lu32;

#define SHUF8(L, H) __builtin_shufflevector(L, H, 0, 1, 2, 3, 4, 5, 6, 7)
#define Z16 {0.f, 0.f, 0.f, 0.f, 0.f, 0.f, 0.f, 0.f, 0.f, 0.f, 0.f, 0.f, 0.f, 0.f, 0.f, 0.f}
#define MXFMA(A, B, C) __builtin_amdgcn_mfma_scale_f32_32x32x64_f8f6f4( \
    A, B, C, 0, 0, 0, 0x7f7f7f7f, 0, 0x7f7f7f7f)

__device__ __forceinline__ void gl2lds16(const void* g, void* l) {
    // async global->LDS, 16B per lane; LDS dest is wave-uniform base + lane*16
    __builtin_amdgcn_global_load_lds((gu32*)g, (lu32*)l, 16, 0, 0);
}

// bare v_exp_f32 (exp2) -- the 1-inst hardware path
__device__ __forceinline__ float hexp2(float x) {
    return __builtin_amdgcn_exp2f(x);
}

// DPP rotate within each 16-lane row (VALU pipe, not DS): dpp_ctrl = 0x120|n.
template <int CTRL>
__device__ __forceinline__ float fdpp(float x) {
    return __int_as_float(__builtin_amdgcn_update_dpp(
        0, __float_as_int(x), CTRL, 0xF, 0xF, true));
}
__device__ __forceinline__ float qmax16(float v) {
    v = fmaxf(v, fdpp<0x128>(v));  // row_ror:8
    v = fmaxf(v, fdpp<0x124>(v));  // row_ror:4
    v = fmaxf(v, fdpp<0x122>(v));  // row_ror:2
    v = fmaxf(v, fdpp<0x121>(v));  // row_ror:1
    return v;
}
__device__ __forceinline__ float qsum16(float v) {
    v += fdpp<0x128>(v);
    v += fdpp<0x124>(v);
    v += fdpp<0x122>(v);
    v += fdpp<0x121>(v);
    return v;
}

// PROVEN swizzle, byte-identical to prior rounds:
// granule q (16B) of row r lands at ((r>>1)*128 + ((((r&1)<<2)|q)^((r>>1)&7))*16
__device__ __forceinline__ int swz(int r, int q) {
    return ((r >> 1) << 7) + (((((r & 1) << 2) | q) ^ ((r >> 1) & 7)) << 4);
}

// ---------------- Kernel 1: fp8 e4m3 quantize + row sum-of-squares of the
// DEQUANTIZED values (sim_ij = -||x^_i - x^_j||^2 - 100*diag exactly) -------
__global__ __launch_bounds__(256) void prep_kernel(const float* __restrict__ x,
                                                   unsigned char* __restrict__ xq,
                                                   float* __restrict__ sq,
                                                   float* __restrict__ out) {
    if (blockIdx.x == 0 && threadIdx.x == 0) out[0] = 0.f;  // for combine's atomics
    const int w = threadIdx.x >> 6, lane = threadIdx.x & 63;
    const int row = blockIdx.x * 4 + w;
    const float4* xr = (const float4*)(x + (size_t)row * GD);
    unsigned int* xqr = (unsigned int*)(xq + (size_t)row * GD);
    float s = 0.f;
#pragma unroll
    for (int i = 0; i < 3; ++i) {
        float4 v = xr[lane + 64 * i];
        unsigned int pk = __builtin_amdgcn_cvt_pk_fp8_f32(v.x, v.y, 0, false);
        pk = __builtin_amdgcn_cvt_pk_fp8_f32(v.z, v.w, pk, true);
        float d0 = __builtin_amdgcn_cvt_f32_fp8(pk, 0);
        float d1 = __builtin_amdgcn_cvt_f32_fp8(pk, 1);
        float d2 = __builtin_amdgcn_cvt_f32_fp8(pk, 2);
        float d3 = __builtin_amdgcn_cvt_f32_fp8(pk, 3);
        s += d0 * d0 + d1 * d1 + d2 * d2 + d3 * d3;
        xqr[lane + 64 * i] = pk;
    }
#pragma unroll
    for (int off = 1; off < 64; off <<= 1) s += __shfl_xor(s, off);
    if (lane == 0) sq[row] = s;
}

// ------- Kernel 2: symmetric triangular tile GEMM (MX-fp8, scale=1.0) + entropy -------
// Round-2 post-mortem: 710 MB scratch writes from f32x16 arrays/subscripts
// (variable extract/insertelement pre-unroll -> alloca). Fix: accumulators are
// 4 NAMED f32x16 values touched only as whole values in the K-loop; after the
// loop they are split via constant-mask shufflevector into f32x4 pa[4][4] --
// the exact (round-0-proven) epilogue data shape. No f32x16 is ever
// subscripted anywhere in this TU.
// 32x32x64 operand layout (HW-verified, absmax 0.0): A row = lane&31, k-half
// = lane>>5 -> granules {2*hi, 2*hi+1}. C/D: col = lane&31, reg e -> row =
// (e&3) + 8*(e>>2) + 4*(lane>>5); quad q=e>>2, rg=e&3.
__global__ __launch_bounds__(256, 3) void sym_gemm_entropy(
    const unsigned char* __restrict__ xq, const float* __restrict__ sq,
    const float* __restrict__ taup, float* __restrict__ pm,
    float* __restrict__ ps, float* __restrict__ pt) {
    __shared__ __align__(16) char lds[32768];  // [A0 8K][B0 8K][A1 8K][B1 8K]
    float (*tmrg)[4][3] = (float (*)[4][3])lds;  // aliased; guarded by barrier

    const int tid = threadIdx.x;
    const int lane = tid & 63;
    const int w = tid >> 6;
    const int cl2 = lane & 31, hi = lane >> 5;

    const int b = blockIdx.x;
    int I = (int)((sqrtf(8.0f * (float)b + 1.0f) - 1.0f) * 0.5f);
    while ((I + 1) * (I + 2) / 2 <= b) ++I;
    while (I * (I + 1) / 2 > b) --I;
    const int J = b - I * (I + 1) / 2;
    const int row_base = I * 128;
    const int col_base = J * 128;
    const float taub = (*taup) * LOG2E;  // base-2 scale

    // staging decode (proven inverse-swizzle)
    const int bb = (tid & 7) ^ ((tid >> 3) & 7);
    const int sRow = ((tid >> 3) << 1) | (bb >> 2);  // 0..63
    const int sKb = (bb & 3) * 16;                   // byte offset in 64-B chunk
    const unsigned char* gA = xq + (size_t)(row_base + sRow) * GD + sKb;
    const unsigned char* gB = xq + (size_t)(col_base + sRow) * GD + sKb;

    // fragment LDS offsets (named scalars): lane reads granules 2*hi, 2*hi+1
    const int offA0 = swz(w * 32 + cl2, 2 * hi);
    const int offA1 = swz(w * 32 + cl2, 2 * hi + 1);
    const int offB00 = swz(0 * 32 + cl2, 2 * hi), offB01 = swz(0 * 32 + cl2, 2 * hi + 1);
    const int offB10 = swz(1 * 32 + cl2, 2 * hi), offB11 = swz(1 * 32 + cl2, 2 * hi + 1);
    const int offB20 = swz(2 * 32 + cl2, 2 * hi), offB21 = swz(2 * 32 + cl2, 2 * hi + 1);
    const int offB30 = swz(3 * 32 + cl2, 2 * hi), offB31 = swz(3 * 32 + cl2, 2 * hi + 1);

    f32x16 acc0 = Z16, acc1 = Z16, acc2 = Z16, acc3 = Z16;

    // prologue: stage k=0 into buffer 0
    gl2lds16(gA, lds + tid * 16);
    gl2lds16(gA + (size_t)64 * GD, lds + 4096 + tid * 16);
    gl2lds16(gB, lds + 8192 + tid * 16);
    gl2lds16(gB + (size_t)64 * GD, lds + 12288 + tid * 16);

#pragma unroll 2
    for (int kk = 0; kk < KI; ++kk) {
        __syncthreads();  // buf[kk&1] staged; prior buf's ds_reads done

        // 1) read ALL fragments of this iter (10 x ds_read_b128); operands
        //    are named values assembled with constant-mask shufflevector
        const char* Ab = lds + (kk & 1) * 16384;
        const char* Bb = Ab + 8192;
        i32x4 aL = *(const i32x4*)(Ab + offA0);
        i32x4 aH = *(const i32x4*)(Ab + offA1);
        i32x4 b0L = *(const i32x4*)(Bb + offB00), b0H = *(const i32x4*)(Bb + offB01);
        i32x4 b1L = *(const i32x4*)(Bb + offB10), b1H = *(const i32x4*)(Bb + offB11);
        i32x4 b2L = *(const i32x4*)(Bb + offB20), b2H = *(const i32x4*)(Bb + offB21);
        i32x4 b3L = *(const i32x4*)(Bb + offB30), b3H = *(const i32x4*)(Bb + offB31);
        i32x8 av = SHUF8(aL, aH);
        i32x8 bv0 = SHUF8(b0L, b0H), bv1 = SHUF8(b1L, b1H);
        i32x8 bv2 = SHUF8(b2L, b2H), bv3 = SHUF8(b3L, b3H);

        // 2) stage k+1 into the other buffer; drains at the next barrier
        if (kk + 1 < KI) {
            char* An = lds + ((kk + 1) & 1) * 16384;
            const int ko = (kk + 1) * 64;  // bytes along K
            gl2lds16(gA + ko, An + tid * 16);
            gl2lds16(gA + (size_t)64 * GD + ko, An + 4096 + tid * 16);
            gl2lds16(gB + ko, An + 8192 + tid * 16);
            gl2lds16(gB + (size_t)64 * GD + ko, An + 12288 + tid * 16);
        }

        // 3) 4 MX MFMAs (K=64, fmt fp8/fp8, scales = 1.0 -> exact fp8 GEMM)
        acc0 = MXFMA(av, bv0, acc0);
        acc1 = MXFMA(av, bv1, acc1);
        acc2 = MXFMA(av, bv2, acc2);
        acc3 = MXFMA(av, bv3, acc3);
    }

    // ---- split named f32x16 accs into round-0-shaped f32x4 quads (constant
    // masks only; the f32x16s die here) ----
    f32x4 pa[4][4];
#define SPLIT16(TJ, A)                                          \
    pa[TJ][0] = __builtin_shufflevector(A, A, 0, 1, 2, 3);      \
    pa[TJ][1] = __builtin_shufflevector(A, A, 4, 5, 6, 7);      \
    pa[TJ][2] = __builtin_shufflevector(A, A, 8, 9, 10, 11);    \
    pa[TJ][3] = __builtin_shufflevector(A, A, 12, 13, 14, 15);
    SPLIT16(0, acc0)
    SPLIT16(1, acc1)
    SPLIT16(2, acc2)
    SPLIT16(3, acc3)
#undef SPLIT16

    // ---------------- epilogue (base-2 state, base-cancelled deltas) ----------------
    const float t2 = 2.f * taub;
    const float pen = 100.f * taub;
    float ar[16];  // -taub * sq[row], indexed [q*4+rg]
#pragma unroll
    for (int q = 0; q < 4; ++q)
#pragma unroll
        for (int rg = 0; rg < 4; ++rg)
            ar[q * 4 + rg] = -taub * sq[row_base + w * 32 + rg + 8 * q + 4 * hi];
    float ac[4];  // -taub * sq[col] for this lane's 4 cols
#pragma unroll
    for (int tj = 0; tj < 4; ++tj) ac[tj] = -taub * sq[col_base + tj * 32 + cl2];

    float* pmJ = pm + (size_t)J * GN;
    float* psJ = ps + (size_t)J * GN;
    float* ptJ = pt + (size_t)J * GN;

    // ---- direct pass: reduce over cols (4 tj in-thread x 32 lanes); the row
    // term is uniform across the reduction -> cancels in d; added once to m ----
#pragma unroll
    for (int q = 0; q < 4; ++q)
#pragma unroll
        for (int rg = 0; rg < 4; ++rg) {
            const int rl = rg + 8 * q + 4 * hi;
            const int rglob = row_base + w * 32 + rl;
            float uu[4];
            float mloc = -1e30f;
            if (I == J) {  // block-uniform: only diagonal tiles carry the penalty
#pragma unroll
                for (int tj = 0; tj < 4; ++tj) {
                    float u = fmaf(t2, pa[tj][q][rg], ac[tj]);
                    if (rglob == col_base + tj * 32 + cl2) u -= pen;
                    uu[tj] = u;
                    mloc = fmaxf(mloc, u);
                }
            } else {
#pragma unroll
                for (int tj = 0; tj < 4; ++tj) {
                    float u = fmaf(t2, pa[tj][q][rg], ac[tj]);
                    uu[tj] = u;
                    mloc = fmaxf(mloc, u);
                }
            }
            mloc = fmaxf(mloc, __shfl_xor(mloc, 16));  // 32-wide max
            mloc = qmax16(mloc);
            float s = 0.f, t = 0.f;
#pragma unroll
            for (int tj = 0; tj < 4; ++tj) {
                float d = uu[tj] - mloc;  // row term cancelled
                float e = hexp2(d);       // bare v_exp_f32
                s += e;
                t += e * d;
            }
            s += __shfl_xor(s, 16);
            t += __shfl_xor(t, 16);
            s = qsum16(s);
            t = qsum16(t);
            if (cl2 == 0) {  // lanes 0 and 32 write disjoint rows
                pmJ[rglob] = mloc + ar[q * 4 + rg];  // base restored once
                psJ[rglob] = s;
                ptJ[rglob] = t;
            }
        }

    // ---- transposed pass: reduce over rows (16 in-thread x 2 hi-halves); col
    // term uniform across the reduction -> cancels in d; added once to m ----
    if (I != J) {  // block-uniform branch
        __syncthreads();  // all K-loop LDS reads done before tmrg aliases the buffer
#pragma unroll
        for (int tj = 0; tj < 4; ++tj) {
            float uu[16];
            float mloc = -1e30f;
#pragma unroll
            for (int q = 0; q < 4; ++q)
#pragma unroll
                for (int rg = 0; rg < 4; ++rg) {
                    float u = fmaf(t2, pa[tj][q][rg], ar[q * 4 + rg]);
                    uu[q * 4 + rg] = u;
                    mloc = fmaxf(mloc, u);
                }
            mloc = fmaxf(mloc, __shfl_xor(mloc, 32));  // combine hi-halves
            float s = 0.f, t = 0.f;
#pragma unroll
            for (int k = 0; k < 16; ++k) {
                float d = uu[k] - mloc;
                float e = hexp2(d);
                s += e;
                t += e * d;
            }
            s += __shfl_xor(s, 32);
            t += __shfl_xor(t, 32);
            if (hi == 0) {
                int c = tj * 32 + cl2;
                tmrg[c][w][0] = mloc + ac[tj];  // col term restored once
                tmrg[c][w][1] = s;
                tmrg[c][w][2] = t;
            }
        }
        __syncthreads();
        if (tid < 128) {
            float m = tmrg[tid][0][0], S = tmrg[tid][0][1], T = tmrg[tid][0][2];
#pragma unroll
            for (int ww = 1; ww < 4; ++ww) {
                float mc = tmrg[tid][ww][0], Sc = tmrg[tid][ww][1], Tc = tmrg[tid][ww][2];
                float mn = fmaxf(m, mc);
                float ea = hexp2(m - mn), eb = hexp2(mc - mn);
                T = (T + (m - mn) * S) * ea + (Tc + (mc - mn) * Sc) * eb;
                S = S * ea + Sc * eb;
                m = mn;
            }
            int c = col_base + tid;
            pm[(size_t)I * GN + c] = m;
            ps[(size_t)I * GN + c] = S;
            pt[(size_t)I * GN + c] = T;
        }
    }
}

// ------- Kernel 3: combine (base-2), coalesced + parallel -------
__global__ __launch_bounds__(256) void combine(const float* __restrict__ pm,
                                               const float* __restrict__ ps,
                                               const float* __restrict__ pt,
                                               const float* __restrict__ coefp,
                                               float* __restrict__ out) {
    const int t = threadIdx.x;
    const int r = t & 63;
    const int chunk = t >> 6;
    const int row = blockIdx.x * 64 + r;
    float m = -1e30f, S = 0.f, T = 0.f;
#pragma unroll
    for (int i = 0; i < 16; ++i) {
        const int c = chunk * 16 + i;
        float mc = pm[(size_t)c * GN + row];
        float Sc = ps[(size_t)c * GN + row];
        float Tc = pt[(size_t)c * GN + row];
        float mn = fmaxf(m, mc);
        float ea = __builtin_amdgcn_exp2f(m - mn), eb = __builtin_amdgcn_exp2f(mc - mn);
        T = (T + (m - mn) * S) * ea + (Tc + (mc - mn) * Sc) * eb;
        S = S * ea + Sc * eb;
        m = mn;
    }
    __shared__ float lm[4][64], lS[4][64], lT[4][64];
    lm[chunk][r] = m;
    lS[chunk][r] = S;
    lT[chunk][r] = T;
    __syncthreads();
    if (t < 64) {
        float M = lm[0][r], Sa = lS[0][r], Ta = lT[0][r];
#pragma unroll
        for (int cc = 1; cc < 4; ++cc) {
            float mc = lm[cc][r], Sc = lS[cc][r], Tc = lT[cc][r];
            float mn = fmaxf(M, mc);
            float ea = __builtin_amdgcn_exp2f(M - mn), eb = __builtin_amdgcn_exp2f(mc - mn);
            Ta = (Ta + (M - mn) * Sa) * ea + (Tc + (mc - mn) * Sc) * eb;
            Sa = Sa * ea + Sc * eb;
            M = mn;
        }
        float ent2 = __log2f(Sa) - Ta / Sa;  // base-2 row entropy (v_log_f32)
#pragma unroll
        for (int off = 1; off < 64; off <<= 1) ent2 += __shfl_xor(ent2, off);
        if (t == 0) atomicAdd(out, ent2 * coefp[0] * (LN2 / (float)GN));
    }
}

extern "C" void kernel_launch(void* const* d_in, const int* in_sizes, int n_in,
                              void* d_out, int out_size, void* d_ws, size_t ws_size,
                              hipStream_t stream) {
    const float* x = (const float*)d_in[0];      // 8192*768 fp32
    const float* coefp = (const float*)d_in[1];  // scalar
    const float* taup = (const float*)d_in[2];   // scalar
    float* out = (float*)d_out;

    char* ws = (char*)d_ws;
    unsigned char* xq = (unsigned char*)ws;              // 6,291,456 B (fp8)
    float* sq = (float*)(ws + 6291456);                  // 32,768 B
    float* pm = (float*)(ws + 6324224);                  // 2,097,152 B
    float* ps = (float*)(ws + 6324224 + 2097152);        // 2,097,152 B
    float* pt = (float*)(ws + 6324224 + 2 * 2097152);    // 2,097,152 B

    prep_kernel<<<GN / 4, 256, 0, stream>>>(x, xq, sq, out);
    sym_gemm_entropy<<<NTILE, 256, 0, stream>>>(xq, sq, taup, pm, ps, pt);
    combine<<<GN / 64, 256, 0, stream>>>(pm, ps, pt, coefp, out);
}